// Round 5
// baseline (300.140 us; speedup 1.0000x reference)
//
#include <hip/hip_runtime.h>
#include <hip/hip_bf16.h>

#define NMODELS 64
#define BBATCH  4096
#define IN_DIM  64
#define H_DIM   256

typedef __attribute__((ext_vector_type(8))) short short8;
typedef __attribute__((ext_vector_type(4))) float floatx4;
typedef __attribute__((ext_vector_type(4))) unsigned int uint4v;
typedef __attribute__((ext_vector_type(2))) unsigned int uint2v;

__device__ __forceinline__ unsigned short f2bf(float f) {   // prep only
    unsigned int u = __builtin_bit_cast(unsigned int, f);
    return (unsigned short)((u + 0x8000u) >> 16);
}
// packed fp32x2 -> bf16x2 (v_cvt_pk_bf16_f32 on gfx950), RNE
__device__ __forceinline__ unsigned int pkbf(float a, float b) {
    __hip_bfloat162 h = __float22bfloat162_rn(make_float2(a, b));
    unsigned int u;
    __builtin_memcpy(&u, &h, 4);
    return u;
}

// Transpose+cvt: W1 [M][64][256]->w1t [M][256][64] bf16 (blocks 0..255)
//                W2 [M][256][256]->w2t [M][256][256] bf16 (blocks 256..1279)
__global__ __launch_bounds__(256) void prep_weights(const float* __restrict__ W1,
                                                    const float* __restrict__ W2,
                                                    unsigned short* __restrict__ w1t,
                                                    unsigned short* __restrict__ w2t) {
    __shared__ float lds[64][65];
    const int bid = blockIdx.x;
    const float* src;
    unsigned short* dst;
    int K, N, m, kb, nb;
    if (bid < 256) {
        m = bid >> 2; kb = 0; nb = bid & 3; K = IN_DIM; N = H_DIM;
        src = W1; dst = w1t;
    } else {
        int t = bid - 256;
        m = t >> 4; kb = (t >> 2) & 3; nb = t & 3; K = H_DIM; N = H_DIM;
        src = W2; dst = w2t;
    }
    const float* s = src + ((size_t)m * K + (size_t)kb * 64) * N + nb * 64;
    const int tid = threadIdx.x;
    const int r = tid >> 4, c4 = (tid & 15) * 4;
#pragma unroll
    for (int p = 0; p < 4; ++p) {
        int row = p * 16 + r;                      // k-local 0..63
        float4 v = *(const float4*)(s + (size_t)row * N + c4);
        lds[row][c4] = v.x; lds[row][c4 + 1] = v.y;
        lds[row][c4 + 2] = v.z; lds[row][c4 + 3] = v.w;
    }
    __syncthreads();
    unsigned short* dbase = dst + ((size_t)m * N + (size_t)nb * 64) * K + kb * 64;
    const int j = tid & 7;                         // k-chunk 0..7
#pragma unroll
    for (int it = 0; it < 2; ++it) {
        int n = it * 32 + (tid >> 3);              // n-local 0..63
        unsigned short tmp[8];
#pragma unroll
        for (int e = 0; e < 8; ++e) tmp[e] = f2bf(lds[j * 8 + e][n]);
        *(short8*)(dbase + (size_t)n * K + j * 8) = *(const short8*)tmp;
    }
}

__device__ __forceinline__ void loadx(const float* __restrict__ xp0, int c16, int q,
                                      float4 (&xr)[4][2][2]) {
#pragma unroll
    for (int rb = 0; rb < 4; ++rb)
#pragma unroll
        for (int kb = 0; kb < 2; ++kb) {
            const float* xp = xp0 + (rb * 16 + c16) * IN_DIM + kb * 32 + q * 8;
            xr[rb][kb][0] = *(const float4*)xp;
            xr[rb][kb][1] = *(const float4*)(xp + 4);
        }
}

__device__ __forceinline__ void cvtx(const float4 (&xr)[4][2][2], short8 (&axd)[4][2]) {
#pragma unroll
    for (int rb = 0; rb < 4; ++rb)
#pragma unroll
        for (int kb = 0; kb < 2; ++kb) {
            const float4 v0 = xr[rb][kb][0], v1 = xr[rb][kb][1];
            uint4v u;
            u[0] = pkbf(v0.x, v0.y); u[1] = pkbf(v0.z, v0.w);
            u[2] = pkbf(v1.x, v1.y); u[3] = pkbf(v1.z, v1.w);
            axd[rb][kb] = __builtin_bit_cast(short8, u);
        }
}

// Persistent fused 3-layer MLP, T=2 per iteration, 4 iterations per WG.
// Grid = 512 WGs (2/CU). XCD-bijective swizzle: wg = (p&7)*64 + (p>>3) so
// each XCD's L2 holds only 8 models' weights (1.25 MB << 4 MB).
// Round-3 spill fix: next-pair x loads are issued in PHASE 3, after pp
// consumes acc (acc dead -> xr's 64 regs fit; peak there ~130). A
// sched_barrier(0) pins the loads below the acc-death point. shfl tree +
// barrier + out-write hide the HBM latency. red in its own 2 KB LDS slab
// (67.5 KB total, still 2 WG/CU) -> 3 barriers/iter instead of 4.
// Reg peak (phase 1): acc 128 + ax 64 + bw 32 + misc ~ 240 <= 256.
__global__ __launch_bounds__(256, 2) void mlp_fused(
    const float* __restrict__ xs,
    const unsigned short* __restrict__ w1t,   // [M][H][IN] bf16
    const float* __restrict__ b1,
    const unsigned short* __restrict__ w2t,   // [M][H][H] bf16 (n-major)
    const float* __restrict__ b2,
    const float* __restrict__ w3,             // [M][H]
    const float* __restrict__ b3,             // [M]
    float* __restrict__ out)                  // [M][B]
{
    __shared__ unsigned short h1s[2][64 * 256];   // 64 KB
    __shared__ float red[2 * 256];                // 2 KB, separate (no overlay hazard)

    const int p  = blockIdx.x;                    // 0..511
    const int wg = (p & 7) * 64 + (p >> 3);       // XCD-contiguous model ranges
    const int m      = wg >> 3;
    const int tpbase = (wg & 7) * 4;              // tile-pairs tpbase..tpbase+3
    const int tid  = threadIdx.x;
    const int w    = tid >> 6;
    const int lane = tid & 63;
    const int q    = lane >> 4;
    const int c16  = lane & 15;
    const int sw   = c16 & 7;

    // loop-invariant loads
    floatx4 b1v = *(const floatx4*)(b1 + m * H_DIM + w * 64 + c16 * 4);
    floatx4 b2v = *(const floatx4*)(b2 + m * H_DIM + w * 64 + c16 * 4);
    floatx4 w3v = *(const floatx4*)(w3 + m * H_DIM + w * 64 + c16 * 4);
    const float b3v = b3[m];

    const unsigned short* w1p = w1t + (size_t)m * (H_DIM * IN_DIM)
                                + (w * 64 + c16 * 4) * IN_DIM + q * 8;
    const unsigned short* w2p = w2t + (size_t)m * (H_DIM * H_DIM)
                                + (w * 64 + c16 * 4) * H_DIM + q * 8;
    const float* xbase = xs + (size_t)m * BBATCH * IN_DIM;

    float4 xr[4][2][2];
    short8 ax[2][4][2];

    // prologue: pair 0 — t0 load+cvt (one cold HBM stall), then issue t1
    {
        const float* x0 = xbase + (size_t)(tpbase * 128) * IN_DIM;
        loadx(x0, c16, q, xr);
        cvtx(xr, ax[0]);
        loadx(x0 + 64 * IN_DIM, c16, q, xr);
    }

    floatx4 acc[2][4][4];
    short8 bv[3][4];

#pragma unroll 1
    for (int i = 0; i < 4; ++i) {
        // head: finish t1 (loads issued last phase-3 / prologue, long landed)
        cvtx(xr, ax[1]);

        // ---------------- Phase 1: h1[t] = relu(x[t] @ W1 + b1) ----------------
#pragma unroll
        for (int t = 0; t < 2; ++t)
#pragma unroll
            for (int rb = 0; rb < 4; ++rb)
#pragma unroll
                for (int nb = 0; nb < 4; ++nb)
                    acc[t][rb][nb] = (floatx4){0.f, 0.f, 0.f, 0.f};
        {
            short8 bw[2][4];                      // W1 frags (L1/L2-hot after i=0)
#pragma unroll
            for (int kb = 0; kb < 2; ++kb)
#pragma unroll
                for (int nb = 0; nb < 4; ++nb)
                    bw[kb][nb] = *(const short8*)(w1p + nb * IN_DIM + kb * 32);
#pragma unroll
            for (int t = 0; t < 2; ++t)
#pragma unroll
                for (int kb = 0; kb < 2; ++kb)
#pragma unroll
                    for (int nb = 0; nb < 4; ++nb)
#pragma unroll
                        for (int rb = 0; rb < 4; ++rb)
                            acc[t][rb][nb] = __builtin_amdgcn_mfma_f32_16x16x32_bf16(
                                ax[t][rb][kb], bw[kb][nb], acc[t][rb][nb], 0, 0, 0);
        }

        // Prefetch phase-2 B slots kb=0,1 (h1-independent): overlap epilogue+barrier
#pragma unroll
        for (int nb = 0; nb < 4; ++nb) bv[0][nb] = *(const short8*)(w2p + nb * H_DIM + 0 * 32);
#pragma unroll
        for (int nb = 0; nb < 4; ++nb) bv[1][nb] = *(const short8*)(w2p + nb * H_DIM + 1 * 32);

        {   // epilogue: bias+relu+packed cvt, 8B ds_write, 16B-chunk XOR swizzle
#pragma unroll
            for (int t = 0; t < 2; ++t)
#pragma unroll
                for (int rb = 0; rb < 4; ++rb)
#pragma unroll
                    for (int r = 0; r < 4; ++r) {
                        float v0 = fmaxf(acc[t][rb][0][r] + b1v[0], 0.f);
                        float v1 = fmaxf(acc[t][rb][1][r] + b1v[1], 0.f);
                        float v2 = fmaxf(acc[t][rb][2][r] + b1v[2], 0.f);
                        float v3 = fmaxf(acc[t][rb][3][r] + b1v[3], 0.f);
                        uint2v u2; u2[0] = pkbf(v0, v1); u2[1] = pkbf(v2, v3);
                        int row = rb * 16 + q * 4 + r;
                        int chunk = (w * 8 + (c16 >> 1)) ^ (row & 7);
                        *(uint2v*)((char*)&h1s[t][0] + row * 512 + chunk * 16 + (c16 & 1) * 8) = u2;
                    }
        }
        __syncthreads();

        // ---------------- Phase 2: h2[t] = relu(h1[t] @ W2 + b2); pipelined B ----
#pragma unroll
        for (int t = 0; t < 2; ++t)
#pragma unroll
            for (int rb = 0; rb < 4; ++rb)
#pragma unroll
                for (int nb = 0; nb < 4; ++nb)
                    acc[t][rb][nb] = (floatx4){0.f, 0.f, 0.f, 0.f};

#pragma unroll
        for (int kb = 0; kb < 8; ++kb) {
            const int cur = kb % 3;
            const int pre = (kb + 2) % 3;
            if (kb < 6) {                         // keep depth-2 in flight
#pragma unroll
                for (int nb = 0; nb < 4; ++nb)
                    bv[pre][nb] = *(const short8*)(w2p + nb * H_DIM + (kb + 2) * 32);
            }
            short8 av[2][4];
#pragma unroll
            for (int t = 0; t < 2; ++t)
#pragma unroll
                for (int rb = 0; rb < 4; ++rb)
                    av[t][rb] = *(const short8*)((char*)&h1s[t][0] + (rb * 16 + c16) * 512
                                                 + (((kb * 4 + q) ^ sw) * 16));
#pragma unroll
            for (int nb = 0; nb < 4; ++nb)
#pragma unroll
                for (int t = 0; t < 2; ++t)
#pragma unroll
                    for (int rb = 0; rb < 4; ++rb)
                        acc[t][rb][nb] = __builtin_amdgcn_mfma_f32_16x16x32_bf16(
                            av[t][rb], bv[cur][nb], acc[t][rb][nb], 0, 0, 0);
        }

        // ---------------- Phase 3: out = h2 @ W3 + b3 (OUT=1), shfl reduce ------
        float pp[2][4][4];
#pragma unroll
        for (int t = 0; t < 2; ++t)
#pragma unroll
            for (int rb = 0; rb < 4; ++rb)
#pragma unroll
                for (int r = 0; r < 4; ++r) pp[t][rb][r] = 0.f;
#pragma unroll
        for (int t = 0; t < 2; ++t)
#pragma unroll
            for (int rb = 0; rb < 4; ++rb)
#pragma unroll
                for (int nb = 0; nb < 4; ++nb)
#pragma unroll
                    for (int r = 0; r < 4; ++r) {
                        float v = fmaxf(acc[t][rb][nb][r] + b2v[nb], 0.f);
                        pp[t][rb][r] += v * w3v[nb];
                    }

        // acc is DEAD past this point. Pin the prefetch below acc's death so
        // the scheduler cannot hoist the loads into the acc-live region
        // (Round-3 spill). xr (64 regs) now coexists only with pp (32).
        __builtin_amdgcn_sched_barrier(0);
        if (i < 3) {   // next-pair t0 loads; latency hides under shfl tree
            const float* xn = xbase + (size_t)((tpbase + i + 1) * 128) * IN_DIM;
            loadx(xn, c16, q, xr);
        }

#pragma unroll
        for (int off = 1; off < 16; off <<= 1)
#pragma unroll
            for (int t = 0; t < 2; ++t)
#pragma unroll
                for (int rb = 0; rb < 4; ++rb)
#pragma unroll
                    for (int r = 0; r < 4; ++r)
                        pp[t][rb][r] += __shfl_xor(pp[t][rb][r], off);

        if (i < 3) {   // finish next-t0 cvt, then issue next-t1; its latency
                       // hides under red/barrier/out + next phase-1 t0 MFMAs
            cvtx(xr, ax[0]);
            const float* xn = xbase + (size_t)((tpbase + i + 1) * 128) * IN_DIM;
            loadx(xn + 64 * IN_DIM, c16, q, xr);
        }

        __syncthreads();               // h1s reads done; order red write/read
        if (c16 == 0) {
#pragma unroll
            for (int t = 0; t < 2; ++t)
#pragma unroll
                for (int rb = 0; rb < 4; ++rb)
#pragma unroll
                    for (int r = 0; r < 4; ++r)
                        red[t * 256 + w * 64 + rb * 16 + q * 4 + r] = pp[t][rb][r];
        }
        __syncthreads();
        if (tid < 128) {
            int t = tid >> 6, rr = tid & 63;
            const float* rt = red + t * 256;
            float s = rt[rr] + rt[64 + rr] + rt[128 + rr] + rt[192 + rr] + b3v;
            out[(size_t)m * BBATCH + (tpbase + i) * 128 + tid] = s;
        }
        // no end barrier needed: red is a separate slab; next red write is two
        // barriers away, and next h1s epilogue-write is after the next barrier.
    }
}

extern "C" void kernel_launch(void* const* d_in, const int* in_sizes, int n_in,
                              void* d_out, int out_size, void* d_ws, size_t ws_size,
                              hipStream_t stream) {
    const float* xs = (const float*)d_in[0];
    const float* W1 = (const float*)d_in[1];
    const float* b1 = (const float*)d_in[2];
    const float* W2 = (const float*)d_in[3];
    const float* b2 = (const float*)d_in[4];
    const float* W3 = (const float*)d_in[5];
    const float* b3 = (const float*)d_in[6];
    float* out = (float*)d_out;

    unsigned short* w1t = (unsigned short*)d_ws;                    // 2 MB
    unsigned short* w2t = w1t + (size_t)NMODELS * H_DIM * IN_DIM;   // 8.4 MB

    prep_weights<<<256 + NMODELS * 16, 256, 0, stream>>>(W1, W2, w1t, w2t);
    mlp_fused<<<NMODELS * 8, 256, 0, stream>>>(xs, w1t, b1, w2t, b2, W3, b3, out);
}

// Round 6
// 258.330 us; speedup vs baseline: 1.1618x; 1.1618x over previous
//
#include <hip/hip_runtime.h>
#include <hip/hip_bf16.h>

#define NMODELS 64
#define BBATCH  4096
#define IN_DIM  64
#define H_DIM   256

typedef __attribute__((ext_vector_type(8))) short short8;
typedef __attribute__((ext_vector_type(4))) float floatx4;
typedef __attribute__((ext_vector_type(4))) unsigned int uint4v;
typedef __attribute__((ext_vector_type(2))) unsigned int uint2v;

__device__ __forceinline__ unsigned short f2bf(float f) {   // prep only
    unsigned int u = __builtin_bit_cast(unsigned int, f);
    return (unsigned short)((u + 0x8000u) >> 16);
}
// packed fp32x2 -> bf16x2 (v_cvt_pk_bf16_f32 on gfx950), RNE
__device__ __forceinline__ unsigned int pkbf(float a, float b) {
    __hip_bfloat162 h = __float22bfloat162_rn(make_float2(a, b));
    unsigned int u;
    __builtin_memcpy(&u, &h, 4);
    return u;
}

// Transpose+cvt: W1 [M][64][256]->w1t [M][256][64] bf16 (blocks 0..255)
//                W2 [M][256][256]->w2t [M][256][256] bf16 (blocks 256..1279)
__global__ __launch_bounds__(256) void prep_weights(const float* __restrict__ W1,
                                                    const float* __restrict__ W2,
                                                    unsigned short* __restrict__ w1t,
                                                    unsigned short* __restrict__ w2t) {
    __shared__ float lds[64][65];
    const int bid = blockIdx.x;
    const float* src;
    unsigned short* dst;
    int K, N, m, kb, nb;
    if (bid < 256) {
        m = bid >> 2; kb = 0; nb = bid & 3; K = IN_DIM; N = H_DIM;
        src = W1; dst = w1t;
    } else {
        int t = bid - 256;
        m = t >> 4; kb = (t >> 2) & 3; nb = t & 3; K = H_DIM; N = H_DIM;
        src = W2; dst = w2t;
    }
    const float* s = src + ((size_t)m * K + (size_t)kb * 64) * N + nb * 64;
    const int tid = threadIdx.x;
    const int r = tid >> 4, c4 = (tid & 15) * 4;
#pragma unroll
    for (int p = 0; p < 4; ++p) {
        int row = p * 16 + r;                      // k-local 0..63
        float4 v = *(const float4*)(s + (size_t)row * N + c4);
        lds[row][c4] = v.x; lds[row][c4 + 1] = v.y;
        lds[row][c4 + 2] = v.z; lds[row][c4 + 3] = v.w;
    }
    __syncthreads();
    unsigned short* dbase = dst + ((size_t)m * N + (size_t)nb * 64) * K + kb * 64;
    const int j = tid & 7;                         // k-chunk 0..7
#pragma unroll
    for (int it = 0; it < 2; ++it) {
        int n = it * 32 + (tid >> 3);              // n-local 0..63
        unsigned short tmp[8];
#pragma unroll
        for (int e = 0; e < 8; ++e) tmp[e] = f2bf(lds[j * 8 + e][n]);
        *(short8*)(dbase + (size_t)n * K + j * 8) = *(const short8*)tmp;
    }
}

// Barrier-free wave-decoupled fused MLP. Each WAVE owns 16 batch-rows x all
// 256 h-cols for 2 tiles (WG = 4 waves x 16 rows = 64 rows/tile, T=2).
// Phase-2 reads only h1 the SAME wave wrote -> zero __syncthreads (same-wave
// LDS RAW ordered by lgkmcnt). Phase-3 reduce is 16-lane, tree 32 ops, out
// stored from registers (no red LDS, no tail). 8 waves/CU fully independent
// -> stalls interleave (round-0's barrier-lockstep was the diagnosed F~24us
// fixed cost). Cost: each wave reads full W1/W2 slice (4x re-read, L1/L2-hot;
// XCD-bijective swizzle keeps each XCD's working set at 8 models ~ 1 MB).
// MFMA tile relabel col = g*64 + c16*4 + nb: identical index algebra to the
// proven round-0 kernel with w -> g. Regs: acc 128 AGPR + arch ~110-130.
__global__ __launch_bounds__(256, 2) void mlp_fused(
    const float* __restrict__ xs,
    const unsigned short* __restrict__ w1t,   // [M][H][IN] bf16 (n-major)
    const float* __restrict__ b1,
    const unsigned short* __restrict__ w2t,   // [M][H][H] bf16 (n-major)
    const float* __restrict__ b2,
    const float* __restrict__ w3,             // [M][H]
    const float* __restrict__ b3,             // [M]
    float* __restrict__ out)                  // [M][B]
{
    // [t][w][row 16][col 256] bf16, XOR-swizzled in 16B chunks within each row
    __shared__ unsigned short h1s[2 * 4 * 16 * 256];   // 64 KB

    const int bid = blockIdx.x;
    const int wg  = (bid & 7) * 256 + (bid >> 3);  // XCD-bijective (2048 = 8*256)
    const int m     = wg >> 5;
    const int tile0 = (wg & 31) * 2;
    const int tid  = threadIdx.x;
    const int w    = tid >> 6;
    const int lane = tid & 63;
    const int q    = lane >> 4;
    const int c16  = lane & 15;
    const int sw   = c16 & 7;

    char* const myLds = (char*)h1s + w * 8192;     // + t*32768 + row*512

    // bias for phase-1 epilogue: n = g*64 + c16*4 + nb
    floatx4 b1v[4];
#pragma unroll
    for (int g = 0; g < 4; ++g)
        b1v[g] = *(const floatx4*)(b1 + m * H_DIM + g * 64 + c16 * 4);
    const float b3v = b3[m];

    // ---------------- Phase 1: h1 = relu(x @ W1 + b1), 16 rows/wave ----------
    const float* xrow = xs + ((size_t)m * BBATCH + (size_t)tile0 * 64 + w * 16) * IN_DIM;
    short8 ax[2][2];                               // A-frags: row=c16, k=q*8
#pragma unroll
    for (int t = 0; t < 2; ++t)
#pragma unroll
        for (int kb = 0; kb < 2; ++kb) {
            const float* xp = xrow + (size_t)t * 64 * IN_DIM + c16 * IN_DIM + kb * 32 + q * 8;
            float4 v0 = *(const float4*)xp;
            float4 v1 = *(const float4*)(xp + 4);
            uint4v u;
            u[0] = pkbf(v0.x, v0.y); u[1] = pkbf(v0.z, v0.w);
            u[2] = pkbf(v1.x, v1.y); u[3] = pkbf(v1.z, v1.w);
            ax[t][kb] = __builtin_bit_cast(short8, u);
        }

    floatx4 acc[2][4][4];                          // [t][g][nb]
#pragma unroll
    for (int t = 0; t < 2; ++t)
#pragma unroll
        for (int g = 0; g < 4; ++g)
#pragma unroll
            for (int nb = 0; nb < 4; ++nb)
                acc[t][g][nb] = (floatx4){0.f, 0.f, 0.f, 0.f};

    const unsigned short* w1p = w1t + (size_t)m * (H_DIM * IN_DIM)
                                + (c16 * 4) * IN_DIM + q * 8;
#pragma unroll
    for (int g = 0; g < 4; ++g) {
        short8 bw[2][4];                           // B-frags: n = g*64+c16*4+nb
#pragma unroll
        for (int kb = 0; kb < 2; ++kb)
#pragma unroll
            for (int nb = 0; nb < 4; ++nb)
                bw[kb][nb] = *(const short8*)(w1p + (size_t)(g * 64 + nb) * IN_DIM + kb * 32);
#pragma unroll
        for (int t = 0; t < 2; ++t)
#pragma unroll
            for (int kb = 0; kb < 2; ++kb)
#pragma unroll
                for (int nb = 0; nb < 4; ++nb)
                    acc[t][g][nb] = __builtin_amdgcn_mfma_f32_16x16x32_bf16(
                        ax[t][kb], bw[kb][nb], acc[t][g][nb], 0, 0, 0);
    }

    // epilogue: bias+relu+packed cvt, 8B ds_write, 16B-chunk XOR swizzle.
    // Value (row=q*4+r, n=g*64+c16*4+nb) -> chunk16 (g*8 + c16>>1)^(row&7).
#pragma unroll
    for (int t = 0; t < 2; ++t)
#pragma unroll
        for (int g = 0; g < 4; ++g)
#pragma unroll
            for (int r = 0; r < 4; ++r) {
                float v0 = fmaxf(acc[t][g][0][r] + b1v[g][0], 0.f);
                float v1 = fmaxf(acc[t][g][1][r] + b1v[g][1], 0.f);
                float v2 = fmaxf(acc[t][g][2][r] + b1v[g][2], 0.f);
                float v3 = fmaxf(acc[t][g][3][r] + b1v[g][3], 0.f);
                uint2v u2; u2[0] = pkbf(v0, v1); u2[1] = pkbf(v2, v3);
                int row = q * 4 + r;
                int chunk = (g * 8 + (c16 >> 1)) ^ (row & 7);
                *(uint2v*)(myLds + t * 32768 + row * 512 + chunk * 16 + (c16 & 1) * 8) = u2;
            }
    // NO barrier: phase-2 reads only this wave's region; lgkmcnt orders RAW.

    // ---------------- Phase 2: h2 = relu(h1 @ W2 + b2) ----------------------
#pragma unroll
    for (int t = 0; t < 2; ++t)
#pragma unroll
        for (int g = 0; g < 4; ++g)
#pragma unroll
            for (int nb = 0; nb < 4; ++nb)
                acc[t][g][nb] = (floatx4){0.f, 0.f, 0.f, 0.f};

    const unsigned short* w2p = w2t + (size_t)m * (H_DIM * H_DIM)
                                + (c16 * 4) * H_DIM + q * 8;
#pragma unroll
    for (int kb = 0; kb < 8; ++kb) {
        short8 av[2];                              // A-frag: row=c16, k=kb*32+q*8
#pragma unroll
        for (int t = 0; t < 2; ++t)
            av[t] = *(const short8*)(myLds + t * 32768 + c16 * 512
                                     + (((kb * 4 + q) ^ sw) * 16));
#pragma unroll
        for (int g = 0; g < 4; ++g) {
            short8 bv[4];                          // B-frag: n = g*64+c16*4+nb
#pragma unroll
            for (int nb = 0; nb < 4; ++nb)
                bv[nb] = *(const short8*)(w2p + (size_t)(g * 64 + nb) * H_DIM + kb * 32);
#pragma unroll
            for (int nb = 0; nb < 4; ++nb)
#pragma unroll
                for (int t = 0; t < 2; ++t)
                    acc[t][g][nb] = __builtin_amdgcn_mfma_f32_16x16x32_bf16(
                        av[t], bv[nb], acc[t][g][nb], 0, 0, 0);
        }
    }

    // ---------------- Phase 3: out = h2 @ W3 + b3 (OUT=1), 16-lane reduce ----
    floatx4 b2v[4], w3v[4];
#pragma unroll
    for (int g = 0; g < 4; ++g) {
        b2v[g] = *(const floatx4*)(b2 + m * H_DIM + g * 64 + c16 * 4);
        w3v[g] = *(const floatx4*)(w3 + m * H_DIM + g * 64 + c16 * 4);
    }
    float pp[2][4];
#pragma unroll
    for (int t = 0; t < 2; ++t)
#pragma unroll
        for (int r = 0; r < 4; ++r) pp[t][r] = 0.f;
#pragma unroll
    for (int t = 0; t < 2; ++t)
#pragma unroll
        for (int g = 0; g < 4; ++g)
#pragma unroll
            for (int nb = 0; nb < 4; ++nb)
#pragma unroll
                for (int r = 0; r < 4; ++r) {
                    float v = fmaxf(acc[t][g][nb][r] + b2v[g][nb], 0.f);
                    pp[t][r] += v * w3v[g][nb];
                }
#pragma unroll
    for (int off = 1; off < 16; off <<= 1)
#pragma unroll
        for (int t = 0; t < 2; ++t)
#pragma unroll
            for (int r = 0; r < 4; ++r)
                pp[t][r] += __shfl_xor(pp[t][r], off);

    if (c16 == 0) {                                // lanes q=0..3 hold rows q*4+r
#pragma unroll
        for (int t = 0; t < 2; ++t) {
            float4 o;
            o.x = pp[t][0] + b3v; o.y = pp[t][1] + b3v;
            o.z = pp[t][2] + b3v; o.w = pp[t][3] + b3v;
            *(float4*)(out + (size_t)m * BBATCH + (size_t)(tile0 + t) * 64
                       + w * 16 + q * 4) = o;
        }
    }
}

extern "C" void kernel_launch(void* const* d_in, const int* in_sizes, int n_in,
                              void* d_out, int out_size, void* d_ws, size_t ws_size,
                              hipStream_t stream) {
    const float* xs = (const float*)d_in[0];
    const float* W1 = (const float*)d_in[1];
    const float* b1 = (const float*)d_in[2];
    const float* W2 = (const float*)d_in[3];
    const float* b2 = (const float*)d_in[4];
    const float* W3 = (const float*)d_in[5];
    const float* b3 = (const float*)d_in[6];
    float* out = (float*)d_out;

    unsigned short* w1t = (unsigned short*)d_ws;                    // 2 MB
    unsigned short* w2t = w1t + (size_t)NMODELS * H_DIM * IN_DIM;   // 8.4 MB

    prep_weights<<<256 + NMODELS * 16, 256, 0, stream>>>(W1, W2, w1t, w2t);
    mlp_fused<<<NMODELS * (BBATCH / 128), 256, 0, stream>>>(xs, w1t, b1, w2t, b2, W3, b3, out);
}

// Round 9
// 177.569 us; speedup vs baseline: 1.6903x; 1.4548x over previous
//
#include <hip/hip_runtime.h>
#include <hip/hip_bf16.h>

#define NMODELS 64
#define BBATCH  4096
#define IN_DIM  64
#define H_DIM   256

typedef __attribute__((ext_vector_type(8))) short short8;
typedef __attribute__((ext_vector_type(4))) float floatx4;
typedef __attribute__((ext_vector_type(4))) unsigned int uint4v;
typedef __attribute__((ext_vector_type(2))) unsigned int uint2v;

__device__ __forceinline__ unsigned short f2bf(float f) {   // prep only
    unsigned int u = __builtin_bit_cast(unsigned int, f);
    return (unsigned short)((u + 0x8000u) >> 16);
}
// packed fp32x2 -> bf16x2 (v_cvt_pk_bf16_f32 on gfx950), RNE
__device__ __forceinline__ unsigned int pkbf(float a, float b) {
    __hip_bfloat162 h = __float22bfloat162_rn(make_float2(a, b));
    unsigned int u;
    __builtin_memcpy(&u, &h, 4);
    return u;
}

// Transpose+cvt: W1 [M][64][256]->w1t [M][256][64] bf16 (blocks 0..255)
//                W2 [M][256][256]->w2t [M][256][256] bf16 (blocks 256..1279)
__global__ __launch_bounds__(256) void prep_weights(const float* __restrict__ W1,
                                                    const float* __restrict__ W2,
                                                    unsigned short* __restrict__ w1t,
                                                    unsigned short* __restrict__ w2t) {
    __shared__ float lds[64][65];
    const int bid = blockIdx.x;
    const float* src;
    unsigned short* dst;
    int K, N, m, kb, nb;
    if (bid < 256) {
        m = bid >> 2; kb = 0; nb = bid & 3; K = IN_DIM; N = H_DIM;
        src = W1; dst = w1t;
    } else {
        int t = bid - 256;
        m = t >> 4; kb = (t >> 2) & 3; nb = t & 3; K = H_DIM; N = H_DIM;
        src = W2; dst = w2t;
    }
    const float* s = src + ((size_t)m * K + (size_t)kb * 64) * N + nb * 64;
    const int tid = threadIdx.x;
    const int r = tid >> 4, c4 = (tid & 15) * 4;
#pragma unroll
    for (int p = 0; p < 4; ++p) {
        int row = p * 16 + r;                      // k-local 0..63
        float4 v = *(const float4*)(s + (size_t)row * N + c4);
        lds[row][c4] = v.x; lds[row][c4 + 1] = v.y;
        lds[row][c4 + 2] = v.z; lds[row][c4 + 3] = v.w;
    }
    __syncthreads();
    unsigned short* dbase = dst + ((size_t)m * N + (size_t)nb * 64) * K + kb * 64;
    const int j = tid & 7;                         // k-chunk 0..7
#pragma unroll
    for (int it = 0; it < 2; ++it) {
        int n = it * 32 + (tid >> 3);              // n-local 0..63
        unsigned short tmp[8];
#pragma unroll
        for (int e = 0; e < 8; ++e) tmp[e] = f2bf(lds[j * 8 + e][n]);
        *(short8*)(dbase + (size_t)n * K + j * 8) = *(const short8*)tmp;
    }
}

// Fused 3-layer MLP, T=2 batch tiles per WG (the proven round-0 structure,
// 101 us) + XCD locality fix. Key diagnosis: round-0's model-major bid ->
// round-robin XCD placement meant every XCD's 4 MB L2 saw all 64 models'
// weights (10.4 MB) -> W2 fragment loads thrashed to L3 (~500-900 cyc),
// uncoverable by the depth-2 bv prefetch at 2 WG/CU. XCD-bijective swizzle
// wg=(bid&7)*256+(bid>>3) gives each XCD 8 contiguous models = 1.3 MB << 4MB
// -> bw/bv become L2 hits (~200 cyc, covered by prefetch). Also: red in its
// own 2 KB slab (2 barriers/WG instead of 3), s_setprio(1) around MFMA
// clusters (2 independent WGs/CU = role diversity), phase-3-only uniform
// loads sunk below phase 1. Everything else byte-identical to round 0.
__global__ __launch_bounds__(256, 2) void mlp_fused(
    const float* __restrict__ xs,
    const unsigned short* __restrict__ w1t,   // [M][H][IN] bf16
    const float* __restrict__ b1,
    const unsigned short* __restrict__ w2t,   // [M][H][H] bf16 (n-major)
    const float* __restrict__ b2,
    const float* __restrict__ w3,             // [M][H]
    const float* __restrict__ b3,             // [M]
    float* __restrict__ out)                  // [M][B]
{
    __shared__ unsigned short h1s[2][64 * 256];   // 64 KB
    __shared__ float red[2 * 256];                // 2 KB separate slab

    const int bid = blockIdx.x;
    const int wg  = (bid & 7) * 256 + (bid >> 3); // XCD-bijective (2048 = 8*256)
    const int m     = wg >> 5;
    const int tile0 = (wg & 31) * 2;              // this WG: tiles tile0, tile0+1
    const int tid = threadIdx.x;
    const int w   = tid >> 6;
    const int lane = tid & 63;
    const int q   = lane >> 4;
    const int c16 = lane & 15;
    const int sw  = c16 & 7;

    // b1 needed in phase-1 epilogue; hoist only it (b2/w3/b3 sunk below)
    floatx4 b1v = *(const floatx4*)(b1 + m * H_DIM + w * 64 + c16 * 4);

    // ---------------- Phase 1: h1[t] = relu(x[t] @ W1 + b1), t=0,1 ----------------
    const float* xrow0 = xs + ((size_t)m * BBATCH + (size_t)tile0 * 64) * IN_DIM;
    const unsigned short* w1p = w1t + (size_t)m * (H_DIM * IN_DIM)
                                + (w * 64 + c16 * 4) * IN_DIM + q * 8;
    const unsigned short* w2p = w2t + (size_t)m * (H_DIM * H_DIM)
                                + (w * 64 + c16 * 4) * H_DIM + q * 8;

    short8 ax[2][4][2];
#pragma unroll
    for (int t = 0; t < 2; ++t)
#pragma unroll
        for (int rb = 0; rb < 4; ++rb)
#pragma unroll
            for (int kb = 0; kb < 2; ++kb) {
                const float* xp = xrow0 + (size_t)t * 64 * IN_DIM
                                  + (rb * 16 + c16) * IN_DIM + kb * 32 + q * 8;
                float4 v0 = *(const float4*)xp;
                float4 v1 = *(const float4*)(xp + 4);
                uint4v u;
                u[0] = pkbf(v0.x, v0.y); u[1] = pkbf(v0.z, v0.w);
                u[2] = pkbf(v1.x, v1.y); u[3] = pkbf(v1.z, v1.w);
                ax[t][rb][kb] = __builtin_bit_cast(short8, u);
            }

    floatx4 acc[2][4][4];
#pragma unroll
    for (int t = 0; t < 2; ++t)
#pragma unroll
        for (int rb = 0; rb < 4; ++rb)
#pragma unroll
            for (int nb = 0; nb < 4; ++nb)
                acc[t][rb][nb] = (floatx4){0.f, 0.f, 0.f, 0.f};

    {
        short8 bw[2][4];                          // shared across both tiles
#pragma unroll
        for (int kb = 0; kb < 2; ++kb)
#pragma unroll
            for (int nb = 0; nb < 4; ++nb)
                bw[kb][nb] = *(const short8*)(w1p + nb * IN_DIM + kb * 32);
        __builtin_amdgcn_s_setprio(1);
#pragma unroll
        for (int t = 0; t < 2; ++t)
#pragma unroll
            for (int kb = 0; kb < 2; ++kb)
#pragma unroll
                for (int nb = 0; nb < 4; ++nb)
#pragma unroll
                    for (int rb = 0; rb < 4; ++rb)
                        acc[t][rb][nb] = __builtin_amdgcn_mfma_f32_16x16x32_bf16(
                            ax[t][rb][kb], bw[kb][nb], acc[t][rb][nb], 0, 0, 0);
        __builtin_amdgcn_s_setprio(0);
    }

    // Prefetch phase-2 B slots kb=0,1 (h1-independent): L2 latency overlaps
    // the epilogue cvt/ds_write and the barrier drain.
    short8 bv[3][4];
#pragma unroll
    for (int nb = 0; nb < 4; ++nb) bv[0][nb] = *(const short8*)(w2p + nb * H_DIM + 0 * 32);
#pragma unroll
    for (int nb = 0; nb < 4; ++nb) bv[1][nb] = *(const short8*)(w2p + nb * H_DIM + 1 * 32);

    // phase-3-only uniform loads: issue here so latency hides under epilogue
    // + barrier + phase 2 (they are consumed only after phase 2).
    floatx4 b2v = *(const floatx4*)(b2 + m * H_DIM + w * 64 + c16 * 4);
    floatx4 w3v = *(const floatx4*)(w3 + m * H_DIM + w * 64 + c16 * 4);
    const float b3v = b3[m];

    {   // epilogue: bias+relu+packed cvt, 8B ds_write per (t,rb,r), 16B-chunk XOR swizzle
#pragma unroll
        for (int t = 0; t < 2; ++t)
#pragma unroll
            for (int rb = 0; rb < 4; ++rb)
#pragma unroll
                for (int r = 0; r < 4; ++r) {
                    float v0 = fmaxf(acc[t][rb][0][r] + b1v[0], 0.f);
                    float v1 = fmaxf(acc[t][rb][1][r] + b1v[1], 0.f);
                    float v2 = fmaxf(acc[t][rb][2][r] + b1v[2], 0.f);
                    float v3 = fmaxf(acc[t][rb][3][r] + b1v[3], 0.f);
                    uint2v u2; u2[0] = pkbf(v0, v1); u2[1] = pkbf(v2, v3);
                    int row = rb * 16 + q * 4 + r;
                    int chunk = (w * 8 + (c16 >> 1)) ^ (row & 7);
                    *(uint2v*)((char*)&h1s[t][0] + row * 512 + chunk * 16 + (c16 & 1) * 8) = u2;
                }
    }
    __syncthreads();

    // ---------------- Phase 2: h2[t] = relu(h1[t] @ W2 + b2); pipelined B ----------
#pragma unroll
    for (int t = 0; t < 2; ++t)
#pragma unroll
        for (int rb = 0; rb < 4; ++rb)
#pragma unroll
            for (int nb = 0; nb < 4; ++nb)
                acc[t][rb][nb] = (floatx4){0.f, 0.f, 0.f, 0.f};

#pragma unroll
    for (int kb = 0; kb < 8; ++kb) {
        const int cur = kb % 3;
        const int pre = (kb + 2) % 3;
        if (kb < 6) {                             // keep depth-2 in flight
#pragma unroll
            for (int nb = 0; nb < 4; ++nb)
                bv[pre][nb] = *(const short8*)(w2p + nb * H_DIM + (kb + 2) * 32);
        }
        short8 av[2][4];
#pragma unroll
        for (int t = 0; t < 2; ++t)
#pragma unroll
            for (int rb = 0; rb < 4; ++rb)
                av[t][rb] = *(const short8*)((char*)&h1s[t][0] + (rb * 16 + c16) * 512
                                             + (((kb * 4 + q) ^ sw) * 16));
        __builtin_amdgcn_s_setprio(1);
#pragma unroll
        for (int nb = 0; nb < 4; ++nb)
#pragma unroll
            for (int t = 0; t < 2; ++t)
#pragma unroll
                for (int rb = 0; rb < 4; ++rb)
                    acc[t][rb][nb] = __builtin_amdgcn_mfma_f32_16x16x32_bf16(
                        av[t][rb], bv[cur][nb], acc[t][rb][nb], 0, 0, 0);
        __builtin_amdgcn_s_setprio(0);
    }

    // ---------------- Phase 3: out = h2 @ W3 + b3 (OUT=1), shfl reduce ----------
    float p[2][4][4];
#pragma unroll
    for (int t = 0; t < 2; ++t)
#pragma unroll
        for (int rb = 0; rb < 4; ++rb)
#pragma unroll
            for (int r = 0; r < 4; ++r) p[t][rb][r] = 0.f;
#pragma unroll
    for (int t = 0; t < 2; ++t)
#pragma unroll
        for (int rb = 0; rb < 4; ++rb)
#pragma unroll
            for (int nb = 0; nb < 4; ++nb)
#pragma unroll
                for (int r = 0; r < 4; ++r) {
                    float v = fmaxf(acc[t][rb][nb][r] + b2v[nb], 0.f);
                    p[t][rb][r] += v * w3v[nb];
                }
#pragma unroll
    for (int off = 1; off < 16; off <<= 1)
#pragma unroll
        for (int t = 0; t < 2; ++t)
#pragma unroll
            for (int rb = 0; rb < 4; ++rb)
#pragma unroll
                for (int r = 0; r < 4; ++r)
                    p[t][rb][r] += __shfl_xor(p[t][rb][r], off);

    if (c16 == 0) {                               // red is a separate slab: no
#pragma unroll                                    // pre-write barrier needed
        for (int t = 0; t < 2; ++t)
#pragma unroll
            for (int rb = 0; rb < 4; ++rb)
#pragma unroll
                for (int r = 0; r < 4; ++r)
                    red[t * 256 + w * 64 + rb * 16 + q * 4 + r] = p[t][rb][r];
    }
    __syncthreads();
    if (tid < 128) {
        int t = tid >> 6, rr = tid & 63;
        const float* rt = red + t * 256;
        float s = rt[rr] + rt[64 + rr] + rt[128 + rr] + rt[192 + rr] + b3v;
        out[(size_t)m * BBATCH + (tile0 + t) * 64 + rr] = s;
    }
}

extern "C" void kernel_launch(void* const* d_in, const int* in_sizes, int n_in,
                              void* d_out, int out_size, void* d_ws, size_t ws_size,
                              hipStream_t stream) {
    const float* xs = (const float*)d_in[0];
    const float* W1 = (const float*)d_in[1];
    const float* b1 = (const float*)d_in[2];
    const float* W2 = (const float*)d_in[3];
    const float* b2 = (const float*)d_in[4];
    const float* W3 = (const float*)d_in[5];
    const float* b3 = (const float*)d_in[6];
    float* out = (float*)d_out;

    unsigned short* w1t = (unsigned short*)d_ws;                    // 2 MB
    unsigned short* w2t = w1t + (size_t)NMODELS * H_DIM * IN_DIM;   // 8.4 MB

    prep_weights<<<256 + NMODELS * 16, 256, 0, stream>>>(W1, W2, w1t, w2t);
    mlp_fused<<<NMODELS * (BBATCH / 128), 256, 0, stream>>>(xs, w1t, b1, w2t, b2, W3, b3, out);
}